// Round 1
// baseline (22.496 us; speedup 1.0000x reference)
//
#include <hip/hip_runtime.h>
#include <math.h>

#define TILE 32
#define DDIM 64
#define PAD 4
#define LDST (DDIM + PAD)  // 68 floats: rows 2 apart differ by 136 floats -> 8 banks apart

__global__ __launch_bounds__(256) void cdist_kernel(
    const float* __restrict__ x, const float* __restrict__ y,
    float* __restrict__ out, int N, int M) {
  __shared__ float xs[TILE][LDST];
  __shared__ float ys[TILE][LDST];

  const int tid = threadIdx.x;
  const int tx = tid & 15;   // 0..15 -> col pair
  const int ty = tid >> 4;   // 0..15 -> row pair
  const int row0 = blockIdx.y * TILE;
  const int col0 = blockIdx.x * TILE;

  // Stage tiles: 32 rows x 16 float4 = 512 float4 loads per tile, 2 per thread.
  #pragma unroll
  for (int l = tid; l < TILE * (DDIM / 4); l += 256) {
    const int r  = l >> 4;
    const int c4 = (l & 15) << 2;
    const float4 vx = *reinterpret_cast<const float4*>(&x[(row0 + r) * DDIM + c4]);
    const float4 vy = *reinterpret_cast<const float4*>(&y[(col0 + r) * DDIM + c4]);
    *reinterpret_cast<float4*>(&xs[r][c4]) = vx;
    *reinterpret_cast<float4*>(&ys[r][c4]) = vy;
  }
  __syncthreads();

  float acc00 = 0.f, acc01 = 0.f, acc10 = 0.f, acc11 = 0.f;
  const int xr0 = 2 * ty, xr1 = 2 * ty + 1;
  const int yr0 = 2 * tx, yr1 = 2 * tx + 1;

  #pragma unroll
  for (int d = 0; d < DDIM; d += 4) {
    const float4 xa = *reinterpret_cast<const float4*>(&xs[xr0][d]);
    const float4 xb = *reinterpret_cast<const float4*>(&xs[xr1][d]);
    const float4 ya = *reinterpret_cast<const float4*>(&ys[yr0][d]);
    const float4 yb = *reinterpret_cast<const float4*>(&ys[yr1][d]);
    float t;
    t = xa.x - ya.x; acc00 = fmaf(t, t, acc00);
    t = xa.y - ya.y; acc00 = fmaf(t, t, acc00);
    t = xa.z - ya.z; acc00 = fmaf(t, t, acc00);
    t = xa.w - ya.w; acc00 = fmaf(t, t, acc00);

    t = xa.x - yb.x; acc01 = fmaf(t, t, acc01);
    t = xa.y - yb.y; acc01 = fmaf(t, t, acc01);
    t = xa.z - yb.z; acc01 = fmaf(t, t, acc01);
    t = xa.w - yb.w; acc01 = fmaf(t, t, acc01);

    t = xb.x - ya.x; acc10 = fmaf(t, t, acc10);
    t = xb.y - ya.y; acc10 = fmaf(t, t, acc10);
    t = xb.z - ya.z; acc10 = fmaf(t, t, acc10);
    t = xb.w - ya.w; acc10 = fmaf(t, t, acc10);

    t = xb.x - yb.x; acc11 = fmaf(t, t, acc11);
    t = xb.y - yb.y; acc11 = fmaf(t, t, acc11);
    t = xb.z - yb.z; acc11 = fmaf(t, t, acc11);
    t = xb.w - yb.w; acc11 = fmaf(t, t, acc11);
  }

  // Coalesced float2 stores: consecutive tx -> consecutive column pairs.
  const int orow0 = row0 + 2 * ty;
  const int ocol  = col0 + 2 * tx;
  float2 r0 = make_float2(sqrtf(acc00), sqrtf(acc01));
  float2 r1 = make_float2(sqrtf(acc10), sqrtf(acc11));
  *reinterpret_cast<float2*>(&out[(long)orow0 * M + ocol])       = r0;
  *reinterpret_cast<float2*>(&out[(long)(orow0 + 1) * M + ocol]) = r1;
}

extern "C" void kernel_launch(void* const* d_in, const int* in_sizes, int n_in,
                              void* d_out, int out_size, void* d_ws, size_t ws_size,
                              hipStream_t stream) {
  const float* x = (const float*)d_in[0];
  const float* y = (const float*)d_in[1];
  float* out = (float*)d_out;
  const int N = in_sizes[0] / DDIM;  // 2048
  const int M = in_sizes[1] / DDIM;  // 2048

  dim3 grid(M / TILE, N / TILE);     // 64 x 64
  dim3 block(256);
  cdist_kernel<<<grid, block, 0, stream>>>(x, y, out, N, M);
}

// Round 2
// 18.985 us; speedup vs baseline: 1.1849x; 1.1849x over previous
//
#include <hip/hip_runtime.h>
#include <hip/hip_bf16.h>
#include <math.h>

#define DD 64  // feature dim

typedef __bf16 bf16x8 __attribute__((ext_vector_type(8)));
typedef float f32x4 __attribute__((ext_vector_type(4)));

// Kernel 1: fp32 -> bf16 conversion + row norms (computed from the bf16-rounded
// values so that dist^2 = ||xb||^2 + ||yb||^2 - 2 xb.yb = ||xb - yb||^2 >= 0).
// One wave (64 lanes) per row, one element per lane.
__global__ __launch_bounds__(256) void convert_norm(
    const float* __restrict__ x, const float* __restrict__ y,
    __hip_bfloat16* __restrict__ xb, __hip_bfloat16* __restrict__ yb,
    float* __restrict__ nx, float* __restrict__ ny, int N, int M) {
  const int w = (blockIdx.x * blockDim.x + threadIdx.x) >> 6;
  const int lane = threadIdx.x & 63;

  const float* src;
  __hip_bfloat16* dst;
  float* nrm;
  int r;
  if (w < N) {
    src = x; dst = xb; nrm = nx; r = w;
  } else {
    r = w - N;
    if (r >= M) return;
    src = y; dst = yb; nrm = ny;
  }

  const float v = src[r * DD + lane];
  const __hip_bfloat16 b = __float2bfloat16(v);
  dst[r * DD + lane] = b;
  const float f = __bfloat162float(b);
  float s = f * f;
  #pragma unroll
  for (int off = 32; off > 0; off >>= 1) s += __shfl_down(s, off, 64);
  if (lane == 0) nrm[r] = s;
}

// Kernel 2: out[i][j] = sqrt(max(nx[i] + ny[j] - 2 * (xb_i . yb_j), 0))
// Block = 256 threads = 4 waves in a 2x2 grid; block tile 128x128; each wave
// computes a 64x64 tile = 4x4 fragments of 16x16, K=64 in 2 MFMA k-steps.
// Operands load directly from global (inputs are L1/L2 resident; 256 KB each).
__global__ __launch_bounds__(256) void cdist_mfma(
    const __hip_bfloat16* __restrict__ xb, const __hip_bfloat16* __restrict__ yb,
    const float* __restrict__ nx, const float* __restrict__ ny,
    float* __restrict__ out, int N, int M) {
  const int lane = threadIdx.x & 63;
  const int wid  = threadIdx.x >> 6;          // 0..3
  const int wr = wid >> 1, wc = wid & 1;      // 2x2 wave grid
  const int i0 = blockIdx.y * 128 + wr * 64;  // wave row base (X rows)
  const int j0 = blockIdx.x * 128 + wc * 64;  // wave col base (Y rows)
  const int lrow = lane & 15;                 // fragment row/col within 16
  const int kgrp = lane >> 4;                 // 0..3, selects 8-wide k slice

  // A/B fragment layout for mfma_f32_16x16x32_bf16: lane l holds 8 contiguous
  // k-elements of row (l&15), k-offset (l>>4)*8. Both X and Y are [row][k]
  // row-major, exactly the "B^T input" GEMM pattern.
  bf16x8 a[4][2], b[4][2];
  #pragma unroll
  for (int m = 0; m < 4; ++m) {
    #pragma unroll
    for (int ks = 0; ks < 2; ++ks) {
      a[m][ks] = *reinterpret_cast<const bf16x8*>(
          &xb[(i0 + m * 16 + lrow) * DD + ks * 32 + kgrp * 8]);
      b[m][ks] = *reinterpret_cast<const bf16x8*>(
          &yb[(j0 + m * 16 + lrow) * DD + ks * 32 + kgrp * 8]);
    }
  }

  f32x4 acc[4][4] = {};
  #pragma unroll
  for (int ks = 0; ks < 2; ++ks) {
    #pragma unroll
    for (int m = 0; m < 4; ++m) {
      #pragma unroll
      for (int n = 0; n < 4; ++n) {
        acc[m][n] = __builtin_amdgcn_mfma_f32_16x16x32_bf16(
            a[m][ks], b[n][ks], acc[m][n], 0, 0, 0);
      }
    }
  }

  // C/D layout (m89-verified): col = lane&15, row = (lane>>4)*4 + reg.
  const int rbase = kgrp * 4;
  float ny_v[4];
  #pragma unroll
  for (int n = 0; n < 4; ++n) ny_v[n] = ny[j0 + n * 16 + lrow];

  #pragma unroll
  for (int m = 0; m < 4; ++m) {
    const float4 nx4 = *reinterpret_cast<const float4*>(&nx[i0 + m * 16 + rbase]);
    const float nxa[4] = {nx4.x, nx4.y, nx4.z, nx4.w};
    #pragma unroll
    for (int r = 0; r < 4; ++r) {
      const int row = i0 + m * 16 + rbase + r;
      float* __restrict__ orow = &out[(long)row * M + j0];
      #pragma unroll
      for (int n = 0; n < 4; ++n) {
        const float d2 = fmaf(-2.0f, acc[m][n][r], nxa[r] + ny_v[n]);
        orow[n * 16 + lrow] = sqrtf(fmaxf(d2, 0.0f));
      }
    }
  }
}

extern "C" void kernel_launch(void* const* d_in, const int* in_sizes, int n_in,
                              void* d_out, int out_size, void* d_ws, size_t ws_size,
                              hipStream_t stream) {
  const float* x = (const float*)d_in[0];
  const float* y = (const float*)d_in[1];
  float* out = (float*)d_out;
  const int N = in_sizes[0] / DD;  // 2048
  const int M = in_sizes[1] / DD;  // 2048

  // Workspace layout (16B aligned slices).
  char* ws = (char*)d_ws;
  __hip_bfloat16* xb = (__hip_bfloat16*)ws;                       // N*DD*2 B
  __hip_bfloat16* yb = (__hip_bfloat16*)(ws + (size_t)N * DD * 2); // M*DD*2 B
  float* nx = (float*)(ws + (size_t)(N + M) * DD * 2);             // N*4 B
  float* ny = (float*)(ws + (size_t)(N + M) * DD * 2 + (size_t)N * 4);

  // Kernel 1: one wave per row, 4 waves per block.
  const int total_waves = N + M;
  convert_norm<<<dim3((total_waves + 3) / 4), dim3(256), 0, stream>>>(
      x, y, xb, yb, nx, ny, N, M);

  // Kernel 2: 128x128 block tiles.
  cdist_mfma<<<dim3(M / 128, N / 128), dim3(256), 0, stream>>>(
      xb, yb, nx, ny, out, N, M);
}